// Round 3
// baseline (197.373 us; speedup 1.0000x reference)
//
#include <hip/hip_runtime.h>

#define T_TOKENS 16384
#define CAP 12288     // per-expert bucket capacity; expected count ~4096
#define CNT_STRIDE 16 // one 64B cacheline per counter

typedef unsigned short u16;
typedef unsigned int u32;
typedef __attribute__((ext_vector_type(8))) short short8;
typedef __attribute__((ext_vector_type(4))) float float4v;

__device__ __forceinline__ u16 f2b(float f) {
  unsigned u = __float_as_uint(f);
  u = (u + 0x7fffu + ((u >> 16) & 1u)) >> 16;   // RNE fp32 -> bf16
  return (u16)u;
}
__device__ __forceinline__ float b2f(u16 h) {
  return __uint_as_float(((unsigned)h) << 16);
}

// async global->LDS, 16B per lane; LDS dest = wave-uniform base + lane*16
__device__ __forceinline__ void gl_lds16(const u16* g, u16* l) {
  __builtin_amdgcn_global_load_lds((const __attribute__((address_space(1))) u32*)g,
                                   (__attribute__((address_space(3))) u32*)l, 16, 0, 0);
}

// ---------------- fp32 -> bf16 conversion of x and all weights; zero cnt ----------------
__global__ void convert_all(const float* __restrict__ x, const float* __restrict__ W1,
                            const float* __restrict__ W2, const float* __restrict__ W3,
                            u16* __restrict__ xb, u16* __restrict__ Wb1,
                            u16* __restrict__ Wb2, u16* __restrict__ Wb3,
                            int* __restrict__ cnt) {
  if (blockIdx.x == 0 && threadIdx.x < 24) cnt[threadIdx.x * CNT_STRIDE] = 0;
  const int nx = T_TOKENS * 512, n1 = 8 * 256 * 512, n2 = 8 * 256 * 256;
  int base = (blockIdx.x * 256 + threadIdx.x) * 8;
  const float* src; u16* dst; int off = base;
  if (base < nx) { src = x; dst = xb; }
  else if (base < nx + n1) { src = W1; dst = Wb1; off = base - nx; }
  else if (base < nx + n1 + n2) { src = W2; dst = Wb2; off = base - nx - n1; }
  else { src = W3; dst = Wb3; off = base - nx - n1 - n2; }
  float4 a0 = *(const float4*)(src + off);
  float4 a1 = *(const float4*)(src + off + 4);
  short8 v;
  v[0] = (short)f2b(a0.x); v[1] = (short)f2b(a0.y);
  v[2] = (short)f2b(a0.z); v[3] = (short)f2b(a0.w);
  v[4] = (short)f2b(a1.x); v[5] = (short)f2b(a1.y);
  v[6] = (short)f2b(a1.z); v[7] = (short)f2b(a1.w);
  *(short8*)(dst + off) = v;
}

// ---------------- routing: block-local LDS histogram + one global atomic batch ----------------
__global__ void route_kernel(const int* __restrict__ m1, const int* __restrict__ m2,
                             const int* __restrict__ m3, const float* __restrict__ rw1,
                             const float* __restrict__ rw2, const float* __restrict__ rw3,
                             int* __restrict__ cnt, int* __restrict__ idxbuf,
                             float* __restrict__ wgtbuf) {
  __shared__ int lcnt[24];
  __shared__ int lbase[24];
  const int tid = threadIdx.x;
  const int t = blockIdx.x * 256 + tid;
  if (tid < 24) lcnt[tid] = 0;
  __syncthreads();

  const int* masks[3] = {m1, m2, m3};
  const float* rws[3] = {rw1, rw2, rw3};
  int expert[3][2], lpos[3][2];
#pragma unroll
  for (int s = 0; s < 3; ++s)
#pragma unroll
    for (int k = 0; k < 2; ++k) {
      int e = 0;
#pragma unroll
      for (int j = 0; j < 8; ++j)
        if (masks[s][(j * 2 + k) * T_TOKENS + t] != 0) e = j;
      expert[s][k] = e;
      lpos[s][k] = atomicAdd(&lcnt[s * 8 + e], 1);
    }
  __syncthreads();
  if (tid < 24) lbase[tid] = atomicAdd(&cnt[tid * CNT_STRIDE], lcnt[tid]);
  __syncthreads();
#pragma unroll
  for (int s = 0; s < 3; ++s)
#pragma unroll
    for (int k = 0; k < 2; ++k) {
      int e = expert[s][k];
      int p = lbase[s * 8 + e] + lpos[s][k];
      if (p < CAP) {
        idxbuf[(s * 8 + e) * CAP + p] = t * 2 + k;
        wgtbuf[(s * 8 + e) * CAP + p] = rws[s][t * 2 + k];
      }
    }
}

// ---------------- grouped gather-GEMM: 128 rows x 256 cols, 256 threads ----------------
// LDS tiles are XOR-swizzled in 16B granules: logical granule lg of row r lives at
// physical granule lg ^ (r&7). This keeps frag ds_reads conflict-spread with NO padding,
// which is required for global_load_lds (wave-uniform base + lane*16 dest).
// SRC==0: A rows = bf16 xb gather (pure async DMA).
// SRC==1: A rows = tmpPrev[t][0][:] + tmpPrev[t][1][:] (fp32 add, re-round, ds_write).
template <int KDIM, int NDIM_TOTAL, int SRC, int RELU>
__global__ __launch_bounds__(256, 2) void moe_gemm(
    const u16* __restrict__ Asrc, const u16* __restrict__ Wb, const float* __restrict__ bias,
    const int* __restrict__ cnt, const int* __restrict__ idxbuf, const float* __restrict__ wgtbuf,
    u16* __restrict__ outTmp) {
  __shared__ __align__(16) u16 As[128 * 64];
  __shared__ __align__(16) u16 Bs[256 * 64];
  __shared__ int rowTok[128];
  __shared__ float rowW[128];

  // locate (expert, row0) for this global row-block index (work exactly covers Sum ceil(n_e/128))
  int b = blockIdx.x;
  int e = -1, row0 = 0, n_e = 0, accb = 0;
#pragma unroll
  for (int j = 0; j < 8; ++j) {
    int nj = cnt[j * CNT_STRIDE];
    nj = nj > CAP ? CAP : nj;
    int nb = (nj + 127) >> 7;
    if (e < 0 && b < accb + nb) { e = j; row0 = (b - accb) << 7; n_e = nj; }
    accb += nb;
  }
  if (e < 0) return;

  const int tid = threadIdx.x;
  if (tid < 128) {
    int g = row0 + tid;
    bool ok = g < n_e;
    rowTok[tid] = ok ? idxbuf[e * CAP + g] : 0;
    rowW[tid] = ok ? wgtbuf[e * CAP + g] : 0.f;
  }
  __syncthreads();

  const int nbase = blockIdx.y * 256;
  const int wv = tid >> 6, lane = tid & 63;
  const int lrow = lane & 15, lquad = lane >> 4;
  const int mh = wv >> 1, nh = wv & 1;

  const u16* Wbe = Wb + ((size_t)e * NDIM_TOTAL + nbase) * KDIM;

  // staging geometry: each wave DMAs 8 rows (1KB) per issue; lane covers row lane>>3,
  // physical granule lane&7 which must hold logical granule (lane&7)^(lane>>3)
  const int lr = lane >> 3;
  const int lgl = (lane & 7) ^ lr;
  const u16* gB = Wbe + (size_t)(wv * 8 + lr) * KDIM + lgl * 8;
  u16* lB = &Bs[(wv * 8) * 64];
  u16* lA = &As[(wv * 8) * 64];

  const u16* gA[4];     // SRC==0: async gather bases
  const u16* ga0[4];    // SRC==1: VGPR-path bases (row pair)
  int awoff[4];
  if (SRC == 0) {
#pragma unroll
    for (int i = 0; i < 4; ++i) {
      int r = i * 32 + wv * 8 + lr;
      gA[i] = Asrc + (size_t)(rowTok[r] >> 1) * KDIM + lgl * 8;
    }
  } else {
#pragma unroll
    for (int i = 0; i < 4; ++i) {
      int r = i * 32 + (tid >> 3);
      ga0[i] = Asrc + (size_t)(rowTok[r] >> 1) * 2 * KDIM + (tid & 7) * 8;
      awoff[i] = (r * 8 + ((tid & 7) ^ ((tid >> 3) & 7))) * 8;
    }
  }

  float4v acc[4][8];
#pragma unroll
  for (int mt = 0; mt < 4; ++mt)
#pragma unroll
    for (int nt = 0; nt < 8; ++nt) acc[mt][nt] = (float4v)0.f;

  for (int kb = 0; kb < KDIM; kb += 64) {
    // ---- B tile (256x64): pure async DMA ----
#pragma unroll
    for (int i = 0; i < 8; ++i)
      gl_lds16(gB + (size_t)i * 32 * KDIM + kb, lB + i * 32 * 64);
    // ---- A tile (128x64) ----
    if (SRC == 0) {
#pragma unroll
      for (int i = 0; i < 4; ++i)
        gl_lds16(gA[i] + kb, lA + i * 32 * 64);
    } else {
#pragma unroll
      for (int i = 0; i < 4; ++i) {
        short8 v0 = *(const short8*)(ga0[i] + kb);
        short8 v1 = *(const short8*)(ga0[i] + kb + KDIM);
        short8 v;
#pragma unroll
        for (int j = 0; j < 8; ++j)
          v[j] = (short)f2b(b2f((u16)v0[j]) + b2f((u16)v1[j]));
        *(short8*)&As[awoff[i]] = v;
      }
    }
    __syncthreads();
    // ---- MFMA: 2 ks-halves x 32 = 64 MFMA / wave ----
#pragma unroll
    for (int ks = 0; ks < 64; ks += 32) {
      const int gb = ks >> 3;
      short8 af[4], bf[8];
#pragma unroll
      for (int mt = 0; mt < 4; ++mt) {
        int r = mh * 64 + mt * 16 + lrow;
        int p = (gb + lquad) ^ (lrow & 7);
        af[mt] = *(const short8*)&As[(r * 8 + p) * 8];
      }
#pragma unroll
      for (int nt = 0; nt < 8; ++nt) {
        int r = nh * 128 + nt * 16 + lrow;
        int p = (gb + lquad) ^ (lrow & 7);
        bf[nt] = *(const short8*)&Bs[(r * 8 + p) * 8];
      }
#pragma unroll
      for (int mt = 0; mt < 4; ++mt)
#pragma unroll
        for (int nt = 0; nt < 8; ++nt)
          acc[mt][nt] = __builtin_amdgcn_mfma_f32_16x16x32_bf16(af[mt], bf[nt], acc[mt][nt], 0, 0, 0);
    }
    __syncthreads();
  }

  // ---- epilogue: w * (relu?)(dot + bias) -> scatter bf16 rows ----
  float bv[8];
#pragma unroll
  for (int nt = 0; nt < 8; ++nt)
    bv[nt] = bias[e * NDIM_TOTAL + nbase + nh * 128 + nt * 16 + lrow];
#pragma unroll
  for (int mt = 0; mt < 4; ++mt)
#pragma unroll
    for (int i = 0; i < 4; ++i) {
      int m = mh * 64 + mt * 16 + lquad * 4 + i;
      if (row0 + m < n_e) {
        float w = rowW[m];
        size_t drow = (size_t)rowTok[m] * NDIM_TOTAL + nbase + nh * 128;
#pragma unroll
        for (int nt = 0; nt < 8; ++nt) {
          float v = acc[mt][nt][i] + bv[nt];
          if (RELU) v = fmaxf(v, 0.f);
          outTmp[drow + nt * 16 + lrow] = f2b(v * w);
        }
      }
    }
}

// ---------------- finalize: out = relu(tmp3[t][0] + tmp3[t][1]) ----------------
__global__ void finalize_kernel(const u16* __restrict__ tmp3, float* __restrict__ out) {
  int f = (blockIdx.x * 256 + threadIdx.x) * 8;
  int t = f >> 9;
  int o = f & 511;
  const u16* p = tmp3 + (size_t)t * 1024 + o;
  short8 v0 = *(const short8*)p;
  short8 v1 = *(const short8*)(p + 512);
  float4 r0, r1;
  r0.x = fmaxf(b2f((u16)v0[0]) + b2f((u16)v1[0]), 0.f);
  r0.y = fmaxf(b2f((u16)v0[1]) + b2f((u16)v1[1]), 0.f);
  r0.z = fmaxf(b2f((u16)v0[2]) + b2f((u16)v1[2]), 0.f);
  r0.w = fmaxf(b2f((u16)v0[3]) + b2f((u16)v1[3]), 0.f);
  r1.x = fmaxf(b2f((u16)v0[4]) + b2f((u16)v1[4]), 0.f);
  r1.y = fmaxf(b2f((u16)v0[5]) + b2f((u16)v1[5]), 0.f);
  r1.z = fmaxf(b2f((u16)v0[6]) + b2f((u16)v1[6]), 0.f);
  r1.w = fmaxf(b2f((u16)v0[7]) + b2f((u16)v1[7]), 0.f);
  *(float4*)(out + f) = r0;
  *(float4*)(out + f + 4) = r1;
}

extern "C" void kernel_launch(void* const* d_in, const int* in_sizes, int n_in,
                              void* d_out, int out_size, void* d_ws, size_t ws_size,
                              hipStream_t stream) {
  const float* x  = (const float*)d_in[0];
  const int* m1   = (const int*)d_in[1];
  const int* m2   = (const int*)d_in[2];
  const int* m3   = (const int*)d_in[3];
  const float* rw1 = (const float*)d_in[4];
  const float* rw2 = (const float*)d_in[5];
  const float* rw3 = (const float*)d_in[6];
  const float* W1 = (const float*)d_in[7];
  const float* b1 = (const float*)d_in[8];
  const float* W2 = (const float*)d_in[9];
  const float* b2 = (const float*)d_in[10];
  const float* W3 = (const float*)d_in[11];
  const float* b3 = (const float*)d_in[12];
  float* out = (float*)d_out;

  char* ws = (char*)d_ws;
  size_t off = 0;
  int* cnt = (int*)(ws + off); off += 24 * CNT_STRIDE * 4;
  u16* xb  = (u16*)(ws + off); off += (size_t)T_TOKENS * 512 * 2;
  u16* Wb1 = (u16*)(ws + off); off += (size_t)8 * 256 * 512 * 2;
  u16* Wb2 = (u16*)(ws + off); off += (size_t)8 * 256 * 256 * 2;
  u16* Wb3 = (u16*)(ws + off); off += (size_t)8 * 512 * 256 * 2;
  u16* tmp1 = (u16*)(ws + off); off += (size_t)T_TOKENS * 2 * 256 * 2;
  u16* tmp2 = (u16*)(ws + off); off += (size_t)T_TOKENS * 2 * 256 * 2;
  u16* tmp3 = (u16*)(ws + off); off += (size_t)T_TOKENS * 2 * 512 * 2;
  int* idxb = (int*)(ws + off); off += (size_t)3 * 8 * CAP * 4;
  float* wgtb = (float*)(ws + off); off += (size_t)3 * 8 * CAP * 4;

  // (x: 8388608) + (W1: 1048576) + (W2: 524288) + (W3: 1048576) = 11010048 elems / 8 / 256
  convert_all<<<5376, 256, 0, stream>>>(x, W1, W2, W3, xb, Wb1, Wb2, Wb3, cnt);
  route_kernel<<<64, 256, 0, stream>>>(m1, m2, m3, rw1, rw2, rw3, cnt, idxb, wgtb);

  // grid.x = max possible row-blocks: Sum ceil(n_e/128) <= 256 + 8
  moe_gemm<512, 256, 0, 0><<<dim3(264, 1), 256, 0, stream>>>(
      xb, Wb1, b1, cnt + 0, idxb + 0, wgtb + 0, tmp1);
  moe_gemm<256, 256, 1, 0><<<dim3(264, 1), 256, 0, stream>>>(
      tmp1, Wb2, b2, cnt + 8 * CNT_STRIDE, idxb + 8 * CAP, wgtb + 8 * CAP, tmp2);
  moe_gemm<256, 512, 1, 1><<<dim3(264, 2), 256, 0, stream>>>(
      tmp2, Wb3, b3, cnt + 16 * CNT_STRIDE, idxb + 16 * CAP, wgtb + 16 * CAP, tmp3);

  finalize_kernel<<<4096, 256, 0, stream>>>(tmp3, out);
}

// Round 6
// 193.123 us; speedup vs baseline: 1.0220x; 1.0220x over previous
//
#include <hip/hip_runtime.h>

#define T_TOKENS 16384
#define CAP 12288     // per-expert bucket capacity; expected ~4096
#define CNT_STRIDE 16 // one 64B cacheline per counter

typedef unsigned short u16;
typedef unsigned int u32;
typedef __attribute__((ext_vector_type(8))) short short8;
typedef __attribute__((ext_vector_type(4))) float float4v;

__device__ __forceinline__ u16 f2b(float f) {
  unsigned u = __float_as_uint(f);
  u = (u + 0x7fffu + ((u >> 16) & 1u)) >> 16;   // RNE fp32 -> bf16
  return (u16)u;
}
__device__ __forceinline__ float b2f(u16 h) {
  return __uint_as_float(((unsigned)h) << 16);
}

// async global->LDS, 16B/lane; LDS dest = wave-uniform base + lane*16
__device__ __forceinline__ void gl_lds16(const u16* g, u16* l) {
  __builtin_amdgcn_global_load_lds((const __attribute__((address_space(1))) u32*)g,
                                   (__attribute__((address_space(3))) u32*)l, 16, 0, 0);
}

// ---------------- fused prep: route (blocks 0..63) || W fp32->bf16 (blocks 64..255) ----------------
__global__ __launch_bounds__(256) void prep_kernel(
    const int* __restrict__ m1, const int* __restrict__ m2, const int* __restrict__ m3,
    const float* __restrict__ rw1, const float* __restrict__ rw2, const float* __restrict__ rw3,
    const float* __restrict__ W1, const float* __restrict__ W2, const float* __restrict__ W3,
    u16* __restrict__ Wb1, u16* __restrict__ Wb2, u16* __restrict__ Wb3,
    int* __restrict__ cnt, int* __restrict__ idxbuf, float* __restrict__ wgtbuf) {
  const int tid = threadIdx.x;
  const int bid = blockIdx.x;
  if (bid < 64) {
    __shared__ int lcnt[24];
    __shared__ int lbase[24];
    if (tid < 24) lcnt[tid] = 0;
    __syncthreads();
    const int t = bid * 256 + tid;
    const int* masks[3] = {m1, m2, m3};
    const float* rws[3] = {rw1, rw2, rw3};
    int expert[3][2], lpos[3][2];
#pragma unroll
    for (int s = 0; s < 3; ++s)
#pragma unroll
      for (int k = 0; k < 2; ++k) {
        int e = 0;
#pragma unroll
        for (int j = 0; j < 8; ++j)
          if (masks[s][(j * 2 + k) * T_TOKENS + t] != 0) e = j;
        expert[s][k] = e;
        lpos[s][k] = atomicAdd(&lcnt[s * 8 + e], 1);
      }
    __syncthreads();
    if (tid < 24) lbase[tid] = atomicAdd(&cnt[tid * CNT_STRIDE], lcnt[tid]);
    __syncthreads();
#pragma unroll
    for (int s = 0; s < 3; ++s)
#pragma unroll
      for (int k = 0; k < 2; ++k) {
        int e = expert[s][k];
        int p = lbase[s * 8 + e] + lpos[s][k];
        if (p < CAP) {
          idxbuf[(s * 8 + e) * CAP + p] = t * 2 + k;
          wgtbuf[(s * 8 + e) * CAP + p] = rws[s][t * 2 + k];
        }
      }
  } else {
    // W1:1048576, W2:524288, W3:1048576 elems; 1280 jobs x 2048 elems over 192 blocks
    for (int j = bid - 64; j < 1280; j += 192) {
      int base = j * 2048 + tid * 8;
      const float* src; u16* dst; int off = base;
      if (base < 1048576) { src = W1; dst = Wb1; }
      else if (base < 1572864) { src = W2; dst = Wb2; off = base - 1048576; }
      else { src = W3; dst = Wb3; off = base - 1572864; }
      float4 a0 = *(const float4*)(src + off);
      float4 a1 = *(const float4*)(src + off + 4);
      short8 v;
      v[0] = (short)f2b(a0.x); v[1] = (short)f2b(a0.y);
      v[2] = (short)f2b(a0.z); v[3] = (short)f2b(a0.w);
      v[4] = (short)f2b(a1.x); v[5] = (short)f2b(a1.y);
      v[6] = (short)f2b(a1.z); v[7] = (short)f2b(a1.w);
      *(short8*)(dst + off) = v;
    }
  }
}

// ---------------- grouped gather-GEMM: 128 rows x 256 cols, 256 threads ----------------
// LDS tiles XOR-swizzled in 16B granules: logical granule lg of row r at physical lg^(r&7)
// (required: global_load_lds needs contiguous lane->LDS layout; no padding).
// SRC==0: A rows gathered from fp32 x, converted in VGPRs, ds_write.
// SRC==1: A rows = slot0+slot1 of prev bf16 tmp (fp32 add, re-round, ds_write).
template <int KDIM, int NDIM_TOTAL, int SRC, int RELU>
__global__ __launch_bounds__(256, 2) void moe_gemm(
    const void* __restrict__ Asrc_, const u16* __restrict__ Wb, const float* __restrict__ bias,
    const int* __restrict__ cnt, const int* __restrict__ idxbuf, const float* __restrict__ wgtbuf,
    u16* __restrict__ outTmp) {
  __shared__ __align__(16) u16 As[128 * 64];
  __shared__ __align__(16) u16 Bs[256 * 64];
  __shared__ int rowTok[128];
  __shared__ float rowW[128];

  // locate (expert, row0) for this row-block index (grid.x covers Sum ceil(n_e/128))
  int b = blockIdx.x;
  int e = -1, row0 = 0, n_e = 0, accb = 0;
#pragma unroll
  for (int j = 0; j < 8; ++j) {
    int nj = cnt[j * CNT_STRIDE];
    nj = nj > CAP ? CAP : nj;
    int nb = (nj + 127) >> 7;
    if (e < 0 && b < accb + nb) { e = j; row0 = (b - accb) << 7; n_e = nj; }
    accb += nb;
  }
  if (e < 0) return;

  const int tid = threadIdx.x;
  if (tid < 128) {
    int g = row0 + tid;
    bool ok = g < n_e;
    rowTok[tid] = ok ? idxbuf[e * CAP + g] : 0;
    rowW[tid] = ok ? wgtbuf[e * CAP + g] : 0.f;
  }
  __syncthreads();

  const int nbase = blockIdx.y * 256;
  const int wv = tid >> 6, lane = tid & 63;
  const int lrow = lane & 15, lquad = lane >> 4;
  const int mh = wv >> 1, nh = wv & 1;

  const u16* Wbe = Wb + ((size_t)e * NDIM_TOTAL + nbase) * KDIM;

  // B staging: each wave DMAs 8 rows (1KB)/issue; lane -> row lane>>3, phys granule lane&7
  // holding logical granule (lane&7)^(lane>>3)
  const int lr = lane >> 3;
  const int lgl = (lane & 7) ^ lr;
  const u16* gB = Wbe + (size_t)(wv * 8 + lr) * KDIM + lgl * 8;
  u16* lB = &Bs[(wv * 8) * 64];

  // A staging bases (VGPR path): thread covers row tid>>3, logical granule tid&7
  const float* ga_f[4];   // SRC==0
  const u16* ga_b[4];     // SRC==1
  int awoff[4];
#pragma unroll
  for (int i = 0; i < 4; ++i) {
    int r = i * 32 + (tid >> 3);
    if (SRC == 0)
      ga_f[i] = (const float*)Asrc_ + (size_t)(rowTok[r] >> 1) * KDIM + (tid & 7) * 8;
    else
      ga_b[i] = (const u16*)Asrc_ + (size_t)(rowTok[r] >> 1) * 2 * KDIM + (tid & 7) * 8;
    awoff[i] = (r * 8 + ((tid & 7) ^ (r & 7))) * 8;
  }

  float4v acc[4][8];
#pragma unroll
  for (int mt = 0; mt < 4; ++mt)
#pragma unroll
    for (int nt = 0; nt < 8; ++nt) acc[mt][nt] = (float4v)0.f;

  for (int kb = 0; kb < KDIM; kb += 64) {
    // ---- B tile (256x64): pure async DMA ----
#pragma unroll
    for (int i = 0; i < 8; ++i)
      gl_lds16(gB + (size_t)i * 32 * KDIM + kb, lB + i * 32 * 64);
    // ---- A tile (128x64) ----
    if (SRC == 0) {
#pragma unroll
      for (int i = 0; i < 4; ++i) {
        float4 a0 = *(const float4*)(ga_f[i] + kb);
        float4 a1 = *(const float4*)(ga_f[i] + kb + 4);
        short8 v;
        v[0] = (short)f2b(a0.x); v[1] = (short)f2b(a0.y);
        v[2] = (short)f2b(a0.z); v[3] = (short)f2b(a0.w);
        v[4] = (short)f2b(a1.x); v[5] = (short)f2b(a1.y);
        v[6] = (short)f2b(a1.z); v[7] = (short)f2b(a1.w);
        *(short8*)&As[awoff[i]] = v;
      }
    } else {
#pragma unroll
      for (int i = 0; i < 4; ++i) {
        short8 v0 = *(const short8*)(ga_b[i] + kb);
        short8 v1 = *(const short8*)(ga_b[i] + kb + KDIM);
        short8 v;
#pragma unroll
        for (int jj = 0; jj < 8; ++jj)
          v[jj] = (short)f2b(b2f((u16)v0[jj]) + b2f((u16)v1[jj]));
        *(short8*)&As[awoff[i]] = v;
      }
    }
    __syncthreads();
    // ---- MFMA: 2 ks-halves x 32 = 64 MFMA / wave ----
#pragma unroll
    for (int ks = 0; ks < 64; ks += 32) {
      const int gb = ks >> 3;
      short8 af[4], bf[8];
#pragma unroll
      for (int mt = 0; mt < 4; ++mt) {
        int r = mh * 64 + mt * 16 + lrow;
        int p = (gb + lquad) ^ (lrow & 7);
        af[mt] = *(const short8*)&As[(r * 8 + p) * 8];
      }
#pragma unroll
      for (int nt = 0; nt < 8; ++nt) {
        int r = nh * 128 + nt * 16 + lrow;
        int p = (gb + lquad) ^ (lrow & 7);
        bf[nt] = *(const short8*)&Bs[(r * 8 + p) * 8];
      }
#pragma unroll
      for (int mt = 0; mt < 4; ++mt)
#pragma unroll
        for (int nt = 0; nt < 8; ++nt)
          acc[mt][nt] = __builtin_amdgcn_mfma_f32_16x16x32_bf16(af[mt], bf[nt], acc[mt][nt], 0, 0, 0);
    }
    __syncthreads();
  }

  // ---- epilogue: w * (relu?)(dot + bias) -> scatter bf16 rows ----
  float bv[8];
#pragma unroll
  for (int nt = 0; nt < 8; ++nt)
    bv[nt] = bias[e * NDIM_TOTAL + nbase + nh * 128 + nt * 16 + lrow];
#pragma unroll
  for (int mt = 0; mt < 4; ++mt)
#pragma unroll
    for (int i = 0; i < 4; ++i) {
      int m = mh * 64 + mt * 16 + lquad * 4 + i;
      if (row0 + m < n_e) {
        float w = rowW[m];
        size_t drow = (size_t)rowTok[m] * NDIM_TOTAL + nbase + nh * 128;
#pragma unroll
        for (int nt = 0; nt < 8; ++nt) {
          float v = acc[mt][nt][i] + bv[nt];
          if (RELU) v = fmaxf(v, 0.f);
          outTmp[drow + nt * 16 + lrow] = f2b(v * w);
        }
      }
    }
}

// ---------------- finalize: out = relu(tmp3[t][0] + tmp3[t][1]) ----------------
__global__ void finalize_kernel(const u16* __restrict__ tmp3, float* __restrict__ out) {
  int f = (blockIdx.x * 256 + threadIdx.x) * 8;
  int t = f >> 9;
  int o = f & 511;
  const u16* p = tmp3 + (size_t)t * 1024 + o;
  short8 v0 = *(const short8*)p;
  short8 v1 = *(const short8*)(p + 512);
  float4 r0, r1;
  r0.x = fmaxf(b2f((u16)v0[0]) + b2f((u16)v1[0]), 0.f);
  r0.y = fmaxf(b2f((u16)v0[1]) + b2f((u16)v1[1]), 0.f);
  r0.z = fmaxf(b2f((u16)v0[2]) + b2f((u16)v1[2]), 0.f);
  r0.w = fmaxf(b2f((u16)v0[3]) + b2f((u16)v1[3]), 0.f);
  r1.x = fmaxf(b2f((u16)v0[4]) + b2f((u16)v1[4]), 0.f);
  r1.y = fmaxf(b2f((u16)v0[5]) + b2f((u16)v1[5]), 0.f);
  r1.z = fmaxf(b2f((u16)v0[6]) + b2f((u16)v1[6]), 0.f);
  r1.w = fmaxf(b2f((u16)v0[7]) + b2f((u16)v1[7]), 0.f);
  *(float4*)(out + f) = r0;
  *(float4*)(out + f + 4) = r1;
}

extern "C" void kernel_launch(void* const* d_in, const int* in_sizes, int n_in,
                              void* d_out, int out_size, void* d_ws, size_t ws_size,
                              hipStream_t stream) {
  const float* x  = (const float*)d_in[0];
  const int* m1   = (const int*)d_in[1];
  const int* m2   = (const int*)d_in[2];
  const int* m3   = (const int*)d_in[3];
  const float* rw1 = (const float*)d_in[4];
  const float* rw2 = (const float*)d_in[5];
  const float* rw3 = (const float*)d_in[6];
  const float* W1 = (const float*)d_in[7];
  const float* b1 = (const float*)d_in[8];
  const float* W2 = (const float*)d_in[9];
  const float* b2 = (const float*)d_in[10];
  const float* W3 = (const float*)d_in[11];
  const float* b3 = (const float*)d_in[12];
  float* out = (float*)d_out;

  char* ws = (char*)d_ws;
  size_t off = 0;
  int* cnt = (int*)(ws + off); off += 24 * CNT_STRIDE * 4;
  u16* Wb1 = (u16*)(ws + off); off += (size_t)8 * 256 * 512 * 2;
  u16* Wb2 = (u16*)(ws + off); off += (size_t)8 * 256 * 256 * 2;
  u16* Wb3 = (u16*)(ws + off); off += (size_t)8 * 512 * 256 * 2;
  u16* tmp1 = (u16*)(ws + off); off += (size_t)T_TOKENS * 2 * 256 * 2;
  u16* tmp2 = (u16*)(ws + off); off += (size_t)T_TOKENS * 2 * 256 * 2;
  u16* tmp3 = (u16*)(ws + off); off += (size_t)T_TOKENS * 2 * 512 * 2;
  int* idxb = (int*)(ws + off); off += (size_t)3 * 8 * CAP * 4;
  float* wgtb = (float*)(ws + off); off += (size_t)3 * 8 * CAP * 4;

  hipMemsetAsync(cnt, 0, 24 * CNT_STRIDE * 4, stream);
  prep_kernel<<<256, 256, 0, stream>>>(m1, m2, m3, rw1, rw2, rw3, W1, W2, W3,
                                       Wb1, Wb2, Wb3, cnt, idxb, wgtb);

  moe_gemm<512, 256, 0, 0><<<dim3(264, 1), 256, 0, stream>>>(
      x, Wb1, b1, cnt + 0, idxb + 0, wgtb + 0, tmp1);
  moe_gemm<256, 256, 1, 0><<<dim3(264, 1), 256, 0, stream>>>(
      tmp1, Wb2, b2, cnt + 8 * CNT_STRIDE, idxb + 8 * CAP, wgtb + 8 * CAP, tmp2);
  moe_gemm<256, 512, 1, 1><<<dim3(264, 2), 256, 0, stream>>>(
      tmp2, Wb3, b3, cnt + 16 * CNT_STRIDE, idxb + 16 * CAP, wgtb + 16 * CAP, tmp3);

  finalize_kernel<<<4096, 256, 0, stream>>>(tmp3, out);
}